// Round 1
// baseline (720.437 us; speedup 1.0000x reference)
//
#include <hip/hip_runtime.h>
#include <cstdint>
#include <math.h>

#define NPTS 2048
#define NBATCH 16
#define KNBR 20

// ws layout (float offsets)
#define OFF_XFT  0u         // [B][N][64]   2097152
#define OFF_T1   2097152u   // [B*N][32]    1048576
#define OFF_W1AF 3145728u   // [32][64]     2048
#define OFF_W1BF 3147776u   // [32][64]     2048
#define OFF_B1F  3149824u   // [32]
#define OFF_W2F  3149856u   // [32][32]     1024
#define OFF_B2F  3150880u   // [32]
#define OFF_IDX  3150912u   // int [B*N][20] 655360

// ---------------- fold BN into weights ----------------
__global__ void fold_kernel(const float* __restrict__ W1, const float* __restrict__ g1,
                            const float* __restrict__ b1, const float* __restrict__ m1,
                            const float* __restrict__ v1, const float* __restrict__ W2,
                            const float* __restrict__ g2, const float* __restrict__ b2,
                            const float* __restrict__ m2, const float* __restrict__ v2,
                            float* __restrict__ W1AF, float* __restrict__ W1BF,
                            float* __restrict__ B1F, float* __restrict__ W2F,
                            float* __restrict__ B2F) {
  const int o = threadIdx.x;
  if (o < 32) {
    const float s1 = g1[o] / sqrtf(v1[o] + 1e-5f);
    const float s2 = g2[o] / sqrtf(v2[o] + 1e-5f);
    B1F[o] = b1[o] - m1[o] * s1;
    B2F[o] = b2[o] - m2[o] * s2;
    for (int c = 0; c < 64; ++c) {
      W1AF[o * 64 + c] = W1[o * 128 + c] * s1;
      W1BF[o * 64 + c] = W1[o * 128 + 64 + c] * s1;
    }
    for (int c = 0; c < 32; ++c) W2F[o * 32 + c] = W2[o * 32 + c] * s2;
  }
}

// ---------------- transpose (B,C=64,N) -> (B,N,C=64) ----------------
__global__ __launch_bounds__(256) void transpose_kernel(const float* __restrict__ in,
                                                        float* __restrict__ outT) {
  __shared__ float tile[64][65];
  const int b = blockIdx.x >> 5;
  const int n0 = (blockIdx.x & 31) << 6;
  const int tx = threadIdx.x & 63;
  const int ty = threadIdx.x >> 6;  // 0..3
  const float* src = in + (size_t)b * 64 * NPTS;
#pragma unroll
  for (int c = ty; c < 64; c += 4) tile[c][tx] = src[(size_t)c * NPTS + n0 + tx];
  __syncthreads();
  float* dst = outT + ((size_t)b * NPTS + n0) * 64;
#pragma unroll
  for (int nn = ty; nn < 64; nn += 4) dst[(size_t)nn * 64 + tx] = tile[tx][nn];
}

// ---------------- t1 = bias1f + W1bf @ center  per point ----------------
__global__ __launch_bounds__(256) void t1_kernel(const float* __restrict__ xfT,
                                                 const float* __restrict__ W1BF,
                                                 const float* __restrict__ B1F,
                                                 float* __restrict__ T1) {
  const int p = blockIdx.x * 256 + threadIdx.x;  // 0..32767
  float acc[32];
#pragma unroll
  for (int o = 0; o < 32; ++o) acc[o] = B1F[o];
  const float* cen = xfT + (size_t)p * 64;
#pragma unroll
  for (int c0 = 0; c0 < 64; c0 += 4) {
    const float4 cv = *(const float4*)(cen + c0);
    const float cc[4] = {cv.x, cv.y, cv.z, cv.w};
#pragma unroll
    for (int o = 0; o < 32; ++o) {
#pragma unroll
      for (int j = 0; j < 4; ++j) acc[o] = fmaf(W1BF[o * 64 + c0 + j], cc[j], acc[o]);
    }
  }
  float* dst = T1 + (size_t)p * 32;
#pragma unroll
  for (int o = 0; o < 32; o += 4) {
    *(float4*)(dst + o) = make_float4(acc[o], acc[o + 1], acc[o + 2], acc[o + 3]);
  }
}

// ---------------- KNN ----------------
// Block: 256 threads = 64 queries x 4 candidate-quadrants. Grid = 16*32.
// Phase A: per-(query,quadrant) top-20 VALUES via branchless max/min ladder.
// Rescan: collect indices with pd >= T (exactly 20, ascending index).
// Phase B: merge 4x20 -> top-20 with (pd, idx) insertion (stable ties).
__device__ __forceinline__ float pd_of(const float4 qp, const float nqxx, const float4 c) {
  const float dot = __fadd_rn(__fadd_rn(__fmul_rn(qp.x, c.x), __fmul_rn(qp.y, c.y)),
                              __fmul_rn(qp.z, c.z));
  return __fsub_rn(__fadd_rn(nqxx, __fmul_rn(2.0f, dot)), c.w);
}

__global__ __launch_bounds__(256, 3) void knn_kernel(const float* __restrict__ xyz,
                                                     int* __restrict__ knn_out) {
  __shared__ float4 spt[NPTS];
  __shared__ int qlist[256 * KNBR];
  const int b = blockIdx.x >> 5;
  const int qbase = (blockIdx.x & 31) << 6;
  const int tid = threadIdx.x;
  const float* src = xyz + (size_t)b * 3 * NPTS;
  for (int i = tid; i < NPTS; i += 256) {
    const float x = src[i], y = src[NPTS + i], z = src[2 * NPTS + i];
    const float xx = __fadd_rn(__fadd_rn(__fmul_rn(x, x), __fmul_rn(y, y)), __fmul_rn(z, z));
    spt[i] = make_float4(x, y, z, xx);
  }
  __syncthreads();

  const int q = qbase + (tid & 63);
  const int quad = tid >> 6;
  const float4 qp = spt[q];
  const float nqxx = -qp.w;
  const int j0 = quad << 9, j1 = j0 + 512;

  float arr[KNBR];
#pragma unroll
  for (int s = 0; s < KNBR; ++s) arr[s] = -INFINITY;
  for (int j = j0; j < j1; ++j) {
    float v = pd_of(qp, nqxx, spt[j]);
#pragma unroll
    for (int s = 0; s < KNBR; ++s) {  // branchless insert (values only)
      const float hi = fmaxf(arr[s], v);
      v = fminf(arr[s], v);
      arr[s] = hi;
    }
  }
  const float T = arr[KNBR - 1];
  int cnt = 0;
  int* myq = qlist + tid * KNBR;
  for (int j = j0; j < j1; ++j) {
    const float pd = pd_of(qp, nqxx, spt[j]);
    if (pd >= T && cnt < KNBR) { myq[cnt] = j; ++cnt; }
  }
  __syncthreads();

  if (tid < 64) {
    float bpd[KNBR];
    int bidx[KNBR];
#pragma unroll
    for (int s = 0; s < KNBR; ++s) { bpd[s] = -INFINITY; bidx[s] = 0; }
    const float4 qp2 = spt[qbase + tid];
    const float nq2 = -qp2.w;
    for (int quad2 = 0; quad2 < 4; ++quad2) {
      for (int jj = 0; jj < KNBR; ++jj) {
        const int id = qlist[((quad2 << 6) | tid) * KNBR + jj];
        const float v = pd_of(qp2, nq2, spt[id]);
        if (v > bpd[KNBR - 1]) {
#pragma unroll
          for (int s = KNBR - 1; s >= 1; --s) {
            const bool c1 = v > bpd[s - 1];
            const float pj = c1 ? bpd[s - 1] : v;
            const int ij = c1 ? bidx[s - 1] : id;
            if (v > bpd[s]) { bpd[s] = pj; bidx[s] = ij; }
          }
          if (v > bpd[0]) { bpd[0] = v; bidx[0] = id; }
        }
      }
    }
    int* dst = knn_out + ((size_t)(b * NPTS + qbase + tid)) * KNBR;
#pragma unroll
    for (int s = 0; s < KNBR; ++s) dst[s] = bidx[s];
  }
}

// ---------------- fused MLP + max-pool + shuffle-write ----------------
// thread = (point, k-quarter). 4 lanes per point -> shfl_xor max-reduce.
__global__ __launch_bounds__(256, 2) void mlp_kernel(const float* __restrict__ ws,
                                                     const int* __restrict__ knn,
                                                     const float* __restrict__ W3,
                                                     float* __restrict__ out) {
  const int t = blockIdx.x * 256 + threadIdx.x;
  const int p = t >> 2;   // point id 0..32767
  const int kq = t & 3;   // k-quarter
  const int b = p >> 11;
  const int n = p & 2047;
  const float* __restrict__ xfT = ws + OFF_XFT;
  const float* __restrict__ t1p = ws + OFF_T1 + (size_t)p * 32;
  const float* __restrict__ W1 = ws + OFF_W1AF;
  const float* __restrict__ W2 = ws + OFF_W2F;
  const float* __restrict__ B2 = ws + OFF_B2F;
  const float* __restrict__ cen = xfT + (size_t)p * 64;

  float hmax[64];
#pragma unroll
  for (int o = 0; o < 64; ++o) hmax[o] = -INFINITY;

  for (int kk = 0; kk < 5; ++kk) {
    const int k = kq * 5 + kk;
    const int nb = knn[p * KNBR + k];
    const float* __restrict__ nbr = xfT + ((size_t)(b << 11) + nb) * 64;

    float h1[32];
#pragma unroll
    for (int o = 0; o < 32; o += 4) {
      const float4 tv = *(const float4*)(t1p + o);
      h1[o] = tv.x; h1[o + 1] = tv.y; h1[o + 2] = tv.z; h1[o + 3] = tv.w;
    }
#pragma unroll
    for (int c0 = 0; c0 < 64; c0 += 8) {
      const float4 a0 = *(const float4*)(nbr + c0);
      const float4 a1 = *(const float4*)(nbr + c0 + 4);
      const float4 b0 = *(const float4*)(cen + c0);
      const float4 b1 = *(const float4*)(cen + c0 + 4);
      const float e[8] = {a0.x - b0.x, a0.y - b0.y, a0.z - b0.z, a0.w - b0.w,
                          a1.x - b1.x, a1.y - b1.y, a1.z - b1.z, a1.w - b1.w};
#pragma unroll
      for (int o = 0; o < 32; ++o) {
#pragma unroll
        for (int j = 0; j < 8; ++j) h1[o] = fmaf(W1[o * 64 + c0 + j], e[j], h1[o]);
      }
    }
#pragma unroll
    for (int o = 0; o < 32; ++o) h1[o] = fmaxf(h1[o], 0.2f * h1[o]);

    float h2[32];
#pragma unroll
    for (int o = 0; o < 32; ++o) {
      float a = B2[o];
#pragma unroll
      for (int c = 0; c < 32; ++c) a = fmaf(W2[o * 32 + c], h1[c], a);
      h2[o] = fmaxf(a, 0.2f * a);
    }
#pragma unroll
    for (int o = 0; o < 64; ++o) {
      float a = 0.f;
#pragma unroll
      for (int c = 0; c < 32; ++c) a = fmaf(W3[o * 32 + c], h2[c], a);
      hmax[o] = fmaxf(hmax[o], a);
    }
  }
#pragma unroll
  for (int o = 0; o < 64; ++o) {
    hmax[o] = fmaxf(hmax[o], __shfl_xor(hmax[o], 1));
    hmax[o] = fmaxf(hmax[o], __shfl_xor(hmax[o], 2));
  }
  if (kq == 0) {
    float* op = out + (size_t)b * (32 * 4096) + 2 * n;
#pragma unroll
    for (int f = 0; f < 64; ++f) {
      const int u = f >> 5, cc = f & 31;
      op[cc * 4096 + u] = hmax[f];
    }
  }
}

extern "C" void kernel_launch(void* const* d_in, const int* in_sizes, int n_in,
                              void* d_out, int out_size, void* d_ws, size_t ws_size,
                              hipStream_t stream) {
  const float* xyz = (const float*)d_in[0];
  const float* xyz_f = (const float*)d_in[1];
  const float* W1 = (const float*)d_in[2];
  const float* g1 = (const float*)d_in[3];
  const float* b1 = (const float*)d_in[4];
  const float* m1 = (const float*)d_in[5];
  const float* v1 = (const float*)d_in[6];
  const float* W2 = (const float*)d_in[7];
  const float* g2 = (const float*)d_in[8];
  const float* b2 = (const float*)d_in[9];
  const float* m2 = (const float*)d_in[10];
  const float* v2 = (const float*)d_in[11];
  const float* W3 = (const float*)d_in[12];
  float* ws = (float*)d_ws;
  float* out = (float*)d_out;
  int* knn = (int*)(ws + OFF_IDX);

  fold_kernel<<<1, 64, 0, stream>>>(W1, g1, b1, m1, v1, W2, g2, b2, m2, v2,
                                    ws + OFF_W1AF, ws + OFF_W1BF, ws + OFF_B1F,
                                    ws + OFF_W2F, ws + OFF_B2F);
  transpose_kernel<<<512, 256, 0, stream>>>(xyz_f, ws + OFF_XFT);
  t1_kernel<<<128, 256, 0, stream>>>(ws + OFF_XFT, ws + OFF_W1BF, ws + OFF_B1F, ws + OFF_T1);
  knn_kernel<<<512, 256, 0, stream>>>(xyz, knn);
  mlp_kernel<<<512, 256, 0, stream>>>(ws, knn, W3, out);
}

// Round 6
// 640.060 us; speedup vs baseline: 1.1256x; 1.1256x over previous
//
#include <hip/hip_runtime.h>
#include <cstdint>
#include <math.h>

#define NPTS 2048
#define NBATCH 16
#define KNBR 20

// ws layout (float offsets)
#define OFF_YT   0u         // [B*N][64]: y(32) | t1c(32)   2097152
#define OFF_W1AF 2097152u   // [32][64]
#define OFF_W1BF 2099200u   // [32][64]
#define OFF_B1F  2101248u   // [32]
#define OFF_W2F  2101280u   // [32][32]
#define OFF_B2F  2102304u   // [32]
#define OFF_IDX  2102336u   // int [B*N][20]

// ---------------- fold BN into weights ----------------
__global__ void fold_kernel(const float* __restrict__ W1, const float* __restrict__ g1,
                            const float* __restrict__ b1, const float* __restrict__ m1,
                            const float* __restrict__ v1, const float* __restrict__ W2,
                            const float* __restrict__ g2, const float* __restrict__ b2,
                            const float* __restrict__ m2, const float* __restrict__ v2,
                            float* __restrict__ W1AF, float* __restrict__ W1BF,
                            float* __restrict__ B1F, float* __restrict__ W2F,
                            float* __restrict__ B2F) {
  const int o = threadIdx.x;
  if (o < 32) {
    const float s1 = g1[o] / sqrtf(v1[o] + 1e-5f);
    const float s2 = g2[o] / sqrtf(v2[o] + 1e-5f);
    B1F[o] = b1[o] - m1[o] * s1;
    B2F[o] = b2[o] - m2[o] * s2;
    for (int c = 0; c < 64; ++c) {
      W1AF[o * 64 + c] = W1[o * 128 + c] * s1;
      W1BF[o * 64 + c] = W1[o * 128 + 64 + c] * s1;
    }
    for (int c = 0; c < 32; ++c) W2F[o * 32 + c] = W2[o * 32 + c] * s2;
  }
}

// ---------------- per-point precompute: y = W1a@xf, t1c = B1 + W1b@xf - y ----------------
// Reads xyz_f directly in (B,C,N) layout: coalesced per-channel columns.
__global__ __launch_bounds__(256) void pre_kernel(const float* __restrict__ xf,
                                                  const float* __restrict__ W1AF,
                                                  const float* __restrict__ W1BF,
                                                  const float* __restrict__ B1F,
                                                  float* __restrict__ yt) {
  const int p = blockIdx.x * 256 + threadIdx.x;  // 0..32767
  const int b = p >> 11, n = p & 2047;
  const float* src = xf + (size_t)b * 64 * NPTS + n;
  float cen[64];
#pragma unroll
  for (int c = 0; c < 64; ++c) cen[c] = src[(size_t)c * NPTS];
  float y[32], t1[32];
#pragma unroll
  for (int o = 0; o < 32; ++o) {
    float a = 0.f;
    float bb = B1F[o];
#pragma unroll
    for (int c = 0; c < 64; ++c) {
      a = fmaf(W1AF[o * 64 + c], cen[c], a);
      bb = fmaf(W1BF[o * 64 + c], cen[c], bb);
    }
    y[o] = a;
    t1[o] = bb - a;
  }
  float* dst = yt + (size_t)p * 64;
#pragma unroll
  for (int o = 0; o < 32; o += 4) {
    *(float4*)(dst + o) = make_float4(y[o], y[o + 1], y[o + 2], y[o + 3]);
    *(float4*)(dst + 32 + o) = make_float4(t1[o], t1[o + 1], t1[o + 2], t1[o + 3]);
  }
}

// ---------------- KNN (VERBATIM round-1 kernel — the one that PASSED) ----------------
// Block: 256 threads = 64 queries x 4 candidate-quadrants. Grid = 16*32.
// Phase A: per-(query,quadrant) top-20 VALUES via branchless max/min ladder.
// Rescan: collect indices with pd >= T (exactly 20, ascending index).
// Phase B: merge 4x20 -> top-20 with (pd, idx) insertion; ascending-j
//          insertion order + strict '>' reproduces top_k's lowest-index ties.
__device__ __forceinline__ float pd_of(const float4 qp, const float nqxx, const float4 c) {
  const float dot = __fadd_rn(__fadd_rn(__fmul_rn(qp.x, c.x), __fmul_rn(qp.y, c.y)),
                              __fmul_rn(qp.z, c.z));
  return __fsub_rn(__fadd_rn(nqxx, __fmul_rn(2.0f, dot)), c.w);
}

__global__ __launch_bounds__(256, 3) void knn_kernel(const float* __restrict__ xyz,
                                                     int* __restrict__ knn_out) {
  __shared__ float4 spt[NPTS];
  __shared__ int qlist[256 * KNBR];
  const int b = blockIdx.x >> 5;
  const int qbase = (blockIdx.x & 31) << 6;
  const int tid = threadIdx.x;
  const float* src = xyz + (size_t)b * 3 * NPTS;
  for (int i = tid; i < NPTS; i += 256) {
    const float x = src[i], y = src[NPTS + i], z = src[2 * NPTS + i];
    const float xx = __fadd_rn(__fadd_rn(__fmul_rn(x, x), __fmul_rn(y, y)), __fmul_rn(z, z));
    spt[i] = make_float4(x, y, z, xx);
  }
  __syncthreads();

  const int q = qbase + (tid & 63);
  const int quad = tid >> 6;
  const float4 qp = spt[q];
  const float nqxx = -qp.w;
  const int j0 = quad << 9, j1 = j0 + 512;

  float arr[KNBR];
#pragma unroll
  for (int s = 0; s < KNBR; ++s) arr[s] = -INFINITY;
  for (int j = j0; j < j1; ++j) {
    float v = pd_of(qp, nqxx, spt[j]);
#pragma unroll
    for (int s = 0; s < KNBR; ++s) {  // branchless insert (values only)
      const float hi = fmaxf(arr[s], v);
      v = fminf(arr[s], v);
      arr[s] = hi;
    }
  }
  const float T = arr[KNBR - 1];
  int cnt = 0;
  int* myq = qlist + tid * KNBR;
  for (int j = j0; j < j1; ++j) {
    const float pd = pd_of(qp, nqxx, spt[j]);
    if (pd >= T && cnt < KNBR) { myq[cnt] = j; ++cnt; }
  }
  __syncthreads();

  if (tid < 64) {
    float bpd[KNBR];
    int bidx[KNBR];
#pragma unroll
    for (int s = 0; s < KNBR; ++s) { bpd[s] = -INFINITY; bidx[s] = 0; }
    const float4 qp2 = spt[qbase + tid];
    const float nq2 = -qp2.w;
    for (int quad2 = 0; quad2 < 4; ++quad2) {
      for (int jj = 0; jj < KNBR; ++jj) {
        const int id = qlist[((quad2 << 6) | tid) * KNBR + jj];
        const float v = pd_of(qp2, nq2, spt[id]);
        if (v > bpd[KNBR - 1]) {
#pragma unroll
          for (int s = KNBR - 1; s >= 1; --s) {
            const bool c1 = v > bpd[s - 1];
            const float pj = c1 ? bpd[s - 1] : v;
            const int ij = c1 ? bidx[s - 1] : id;
            if (v > bpd[s]) { bpd[s] = pj; bidx[s] = ij; }
          }
          if (v > bpd[0]) { bpd[0] = v; bidx[0] = id; }
        }
      }
    }
    int* dst = knn_out + ((size_t)(b * NPTS + qbase + tid)) * KNBR;
#pragma unroll
    for (int s = 0; s < KNBR; ++s) dst[s] = bidx[s];
  }
}

// ---------------- fused MLP + max-pool + shuffle-write ----------------
__global__ __launch_bounds__(256, 2) void mlp_kernel(const float* __restrict__ ws,
                                                     const int* __restrict__ knn,
                                                     const float* __restrict__ W3,
                                                     float* __restrict__ out) {
  const int t = blockIdx.x * 256 + threadIdx.x;
  const int p = t >> 2;   // point id 0..32767
  const int kq = t & 3;   // k-quarter
  const int b = p >> 11;
  const int n = p & 2047;
  const float* __restrict__ yt = ws + OFF_YT;
  const float* __restrict__ W2 = ws + OFF_W2F;
  const float* __restrict__ B2 = ws + OFF_B2F;
  const float* __restrict__ ybase = yt + ((size_t)(b << 11)) * 64;

  float t1c[32];
  {
    const float* tp = yt + (size_t)p * 64 + 32;
#pragma unroll
    for (int o = 0; o < 32; o += 4) {
      const float4 v = *(const float4*)(tp + o);
      t1c[o] = v.x; t1c[o + 1] = v.y; t1c[o + 2] = v.z; t1c[o + 3] = v.w;
    }
  }
  float hmax[64];
#pragma unroll
  for (int o = 0; o < 64; ++o) hmax[o] = -INFINITY;

#pragma unroll 1  // rolled: keep code in I-cache
  for (int kk = 0; kk < 5; ++kk) {
    // & 2047: insurance — a bad index becomes a wrong answer, not an abort.
    const int nb = knn[p * KNBR + kq * 5 + kk] & 2047;
    const float* __restrict__ yp = ybase + (size_t)nb * 64;

    float h1[32];
#pragma unroll
    for (int o = 0; o < 32; o += 4) {
      const float4 v = *(const float4*)(yp + o);
      h1[o] = t1c[o] + v.x;
      h1[o + 1] = t1c[o + 1] + v.y;
      h1[o + 2] = t1c[o + 2] + v.z;
      h1[o + 3] = t1c[o + 3] + v.w;
    }
#pragma unroll
    for (int o = 0; o < 32; ++o) h1[o] = fmaxf(h1[o], 0.2f * h1[o]);

    float h2[32];
#pragma unroll
    for (int o = 0; o < 32; ++o) {
      float a = B2[o];
#pragma unroll
      for (int c = 0; c < 32; ++c) a = fmaf(W2[o * 32 + c], h1[c], a);
      h2[o] = fmaxf(a, 0.2f * a);
    }
#pragma unroll
    for (int o = 0; o < 64; ++o) {
      float a = 0.f;
#pragma unroll
      for (int c = 0; c < 32; ++c) a = fmaf(W3[o * 32 + c], h2[c], a);
      hmax[o] = fmaxf(hmax[o], a);
    }
  }
#pragma unroll
  for (int o = 0; o < 64; ++o) {
    hmax[o] = fmaxf(hmax[o], __shfl_xor(hmax[o], 1));
    hmax[o] = fmaxf(hmax[o], __shfl_xor(hmax[o], 2));
  }
  if (kq == 0) {
    float* op = out + (size_t)b * (32 * 4096) + 2 * n;
#pragma unroll
    for (int f = 0; f < 64; ++f) {
      const int u = f >> 5, cc = f & 31;
      op[cc * 4096 + u] = hmax[f];
    }
  }
}

extern "C" void kernel_launch(void* const* d_in, const int* in_sizes, int n_in,
                              void* d_out, int out_size, void* d_ws, size_t ws_size,
                              hipStream_t stream) {
  const float* xyz = (const float*)d_in[0];
  const float* xyz_f = (const float*)d_in[1];
  const float* W1 = (const float*)d_in[2];
  const float* g1 = (const float*)d_in[3];
  const float* b1 = (const float*)d_in[4];
  const float* m1 = (const float*)d_in[5];
  const float* v1 = (const float*)d_in[6];
  const float* W2 = (const float*)d_in[7];
  const float* g2 = (const float*)d_in[8];
  const float* b2 = (const float*)d_in[9];
  const float* m2 = (const float*)d_in[10];
  const float* v2 = (const float*)d_in[11];
  const float* W3 = (const float*)d_in[12];
  float* ws = (float*)d_ws;
  float* out = (float*)d_out;
  int* knn = (int*)(ws + OFF_IDX);

  fold_kernel<<<1, 64, 0, stream>>>(W1, g1, b1, m1, v1, W2, g2, b2, m2, v2,
                                    ws + OFF_W1AF, ws + OFF_W1BF, ws + OFF_B1F,
                                    ws + OFF_W2F, ws + OFF_B2F);
  pre_kernel<<<128, 256, 0, stream>>>(xyz_f, ws + OFF_W1AF, ws + OFF_W1BF, ws + OFF_B1F,
                                      ws + OFF_YT);
  knn_kernel<<<512, 256, 0, stream>>>(xyz, knn);
  mlp_kernel<<<512, 256, 0, stream>>>(ws, knn, W3, out);
}